// Round 16
// baseline (31.118 us; speedup 1.0000x reference)
//
#include <hip/hip_runtime.h>

#define B_N   2048
#define LQ    10
#define LH    150

typedef float pf2 __attribute__((ext_vector_type(2)));

// ws float layout:
//   [0..17]   eff_w (ch*9+ky*3+kx)     [18] eff_b      [19..27] fw
//   [30..119] qwpk: float2[45]  {q_w[2ap][t], q_w[2ap+1][t]}, idx=ap*9+t
//   [120..209] wpk: float2[45]  {w[2ap][t],  w[2ap+1][t]},   idx=ap*9+t
#define QWPK 30
#define WPK  120

// ---------------- pre-kernel (1 block x 256 thr) ----------------
// Coalesced LDS staging first (one cold-HBM latency instead of 19 strided
// rounds), then parallel reduce from LDS.
// R15 BUG FIXED: r_w[106..149] were never staged (the else-if branch capped
// at t<256); lanes 0..149 now stage h_b AND r_w.
__global__ __launch_bounds__(256) void vin_precompute(
    const float* __restrict__ h_w, const float* __restrict__ h_b,
    const float* __restrict__ r_w, const float* __restrict__ q_w,
    const float* __restrict__ w,   const float* __restrict__ fc_w,
    float* __restrict__ ws)
{
    __shared__ float l[3000];   // [0,2700) h_w, [2700,2850) h_b, [2850,3000) r_w
    const int t = threadIdx.x;
    #pragma unroll
    for (int k = 0; k < 11; ++k) {
        int idx = t + (k << 8);
        if (idx < 2700) l[idx] = h_w[idx];
    }
    if (t < 150) {
        l[2700 + t] = h_b[t];
        l[2850 + t] = r_w[t];
    }
    __syncthreads();

    if (t < 152) {
        const int tap = t >> 3, j = t & 7;   // 19 outputs x 8 lanes
        float acc = 0.f;
        for (int h = j; h < LH; h += 8)
            acc += l[2850 + h] * (tap < 18 ? l[h * 18 + tap] : l[2700 + h]);
        acc += __shfl_down(acc, 4, 8);
        acc += __shfl_down(acc, 2, 8);
        acc += __shfl_down(acc, 1, 8);
        if (j == 0) ws[tap] = acc;
    } else if (t < 161) {
        const int tt = t - 152;
        float acc = 0.f;
        #pragma unroll
        for (int a = 0; a < LQ; ++a) acc += fc_w[a] * w[a * 9 + tt];
        ws[19 + tt] = acc;
    } else if (t < 206) {
        const int idx = t - 161, ap = idx / 9, tt = idx - ap * 9;
        ws[QWPK + 2 * idx]     = q_w[(2 * ap)     * 9 + tt];
        ws[QWPK + 2 * idx + 1] = q_w[(2 * ap + 1) * 9 + tt];
    } else if (t < 251) {
        const int idx = t - 206, ap = idx / 9, tt = idx - ap * 9;
        ws[WPK + 2 * idx]     = w[(2 * ap)     * 9 + tt];
        ws[WPK + 2 * idx + 1] = w[(2 * ap + 1) * 9 + tt];
    }
}

// ---------------- main kernel ----------------
// ONE WAVE per batch element (2048 blocks x 64 thr, 2 waves/SIMD).
// lane = rg*16 + c; rg owns pixel rows 4rg..4rg+3, col c.
// Register-resident barrier-free VI (R14), prologue leaned out (R15):
// r never touches LDS (shuffle halo), only the 136 read-border cells of X
// are zeroed (disjoint from staged interior -> single prologue barrier).
// LDS: XS only — padded X, ch*648 + (row+1)*36 + (col+1), stride 36.
// No runtime indexing into register arrays (round-4 lesson).
#define ST    36
#define SMEMN 1296

__device__ __forceinline__ float dpp_left(float x) {   // value from col c-1; 0 at c==0
    return __int_as_float(__builtin_amdgcn_update_dpp(
        0, __float_as_int(x), 0x111, 0xF, 0xF, true));  // row_shr:1
}
__device__ __forceinline__ float dpp_right(float x) {  // value from col c+1; 0 at c==15
    return __int_as_float(__builtin_amdgcn_update_dpp(
        0, __float_as_int(x), 0x101, 0xF, 0xF, true));  // row_shl:1
}

__global__ __launch_bounds__(64, 2) void vin_kernel(
    const float* __restrict__ X,   const float* __restrict__ S1,
    const float* __restrict__ S2,  const float* __restrict__ fcw,
    const float* __restrict__ ws,  float* __restrict__ out)
{
    __shared__ float smem[SMEMN];

    const int lane = threadIdx.x;
    const int rg   = lane >> 4;
    const int c    = lane & 15;
    const int b    = blockIdx.x;

    // ---- issue all global loads first ----
    const float* Xb = X + (size_t)b * 512;
    float xreg[8];
    #pragma unroll
    for (int k = 0; k < 8; ++k) xreg[k] = Xb[lane + (k << 6)];
    const float s1f = S1[b], s2f = S2[b];

    // ---- collapsed weights via uniform s_loads ----
    float ew[19];
    #pragma unroll
    for (int tt = 0; tt < 19; ++tt) ew[tt] = ws[tt];

    // ---- zero ONLY the read-border cells (disjoint from staged interior) ----
    #pragma unroll
    for (int ch = 0; ch < 2; ++ch) {
        float* Bc = smem + ch * 648;
        if (lane < 18)      { Bc[lane] = 0.f; Bc[17 * ST + lane] = 0.f; }
        else if (lane < 34) { const int r = lane - 17; Bc[r * ST] = 0.f; Bc[r * ST + 17] = 0.f; }
    }

    // ---- stage X (interior cells only; disjoint from border-zero) ----
    #pragma unroll
    for (int k = 0; k < 8; ++k) {
        int e = lane + (k << 6);
        int ch = e >> 8, rem = e & 255;
        smem[ch * 648 + ((rem >> 4) + 1) * ST + (rem & 15) + 1] = xreg[k];
    }
    __syncthreads();                       // single prologue barrier

    // ---- r = conv3x3(X, eff_w) + eff_b for this lane's 4 rows (in regs) ----
    float rr0, rr1, rr2, rr3;
    {
        const float* xb = smem + (rg << 2) * ST + c;
        float xt[2][6][3];
        #pragma unroll
        for (int ch = 0; ch < 2; ++ch)
            #pragma unroll
            for (int dy = 0; dy < 6; ++dy)
                #pragma unroll
                for (int dx = 0; dx < 3; ++dx)
                    xt[ch][dy][dx] = xb[ch * 648 + dy * ST + dx];

        #pragma unroll
        for (int k = 0; k < 4; ++k) {
            float acc = ew[18];
            #pragma unroll
            for (int ch = 0; ch < 2; ++ch)
                #pragma unroll
                for (int ky = 0; ky < 3; ++ky)
                    #pragma unroll
                    for (int kx = 0; kx < 3; ++kx)
                        acc += xt[ch][k + ky][kx] * ew[ch * 9 + ky * 3 + kx];
            if (k == 0) rr0 = acc; else if (k == 1) rr1 = acc;
            else if (k == 2) rr2 = acc; else rr3 = acc;
        }
    }

    const bool top0 = (rg == 0), bot0 = (rg == 3);
    const int  upL  = (lane - 16) & 63;
    const int  dnL  = (lane + 16) & 63;

    // ---- r halo via shuffle machinery (no LDS round-trip) ----
    float S[6], L[6], R[6];
    {
        float t_ = __shfl(rr3, upL, 64);
        float b_ = __shfl(rr0, dnL, 64);
        S[0] = top0 ? 0.f : t_;
        S[1] = rr0; S[2] = rr1; S[3] = rr2; S[4] = rr3;
        S[5] = bot0 ? 0.f : b_;
        #pragma unroll
        for (int j = 0; j < 6; ++j) { L[j] = dpp_left(S[j]); R[j] = dpp_right(S[j]); }
    }

    // ---- qr2[k][ap] = packed conv3x3(r, q_w) (iteration-invariant) ----
    const pf2* qwp = (const pf2*)(ws + QWPK);
    const pf2* wpk = (const pf2*)(ws + WPK);

    pf2 qr2[4][5];
    #pragma unroll
    for (int k = 0; k < 4; ++k)
        #pragma unroll
        for (int ap = 0; ap < 5; ++ap) {
            pf2 acc = {0.f, 0.f};
            #pragma unroll
            for (int dy = 0; dy < 3; ++dy) {
                const float tl = L[k + dy], ts = S[k + dy], tr = R[k + dy];
                pf2 vl = {tl, tl}, vs = {ts, ts}, vr = {tr, tr};
                acc = __builtin_elementwise_fma(vl, qwp[ap * 9 + dy * 3 + 0], acc);
                acc = __builtin_elementwise_fma(vs, qwp[ap * 9 + dy * 3 + 1], acc);
                acc = __builtin_elementwise_fma(vr, qwp[ap * 9 + dy * 3 + 2], acc);
            }
            qr2[k][ap] = acc;
        }

    // ---- v0 = max over 10 actions, register-resident ----
    float vv0, vv1, vv2, vv3;
    {
        pf2 m0 = __builtin_elementwise_max(
                     __builtin_elementwise_max(qr2[0][0], qr2[0][1]),
                     __builtin_elementwise_max(qr2[0][2], qr2[0][3]));
        m0 = __builtin_elementwise_max(m0, qr2[0][4]);
        vv0 = fmaxf(m0.x, m0.y);
        pf2 m1 = __builtin_elementwise_max(
                     __builtin_elementwise_max(qr2[1][0], qr2[1][1]),
                     __builtin_elementwise_max(qr2[1][2], qr2[1][3]));
        m1 = __builtin_elementwise_max(m1, qr2[1][4]);
        vv1 = fmaxf(m1.x, m1.y);
        pf2 m2 = __builtin_elementwise_max(
                     __builtin_elementwise_max(qr2[2][0], qr2[2][1]),
                     __builtin_elementwise_max(qr2[2][2], qr2[2][3]));
        m2 = __builtin_elementwise_max(m2, qr2[2][4]);
        vv2 = fmaxf(m2.x, m2.y);
        pf2 m3 = __builtin_elementwise_max(
                     __builtin_elementwise_max(qr2[3][0], qr2[3][1]),
                     __builtin_elementwise_max(qr2[3][2], qr2[3][3]));
        m3 = __builtin_elementwise_max(m3, qr2[3][4]);
        vv3 = fmaxf(m3.x, m3.y);
    }

    // S[j] = own-column v at pixel row 4rg-1+j; L/R = cols c-1/c+1 via DPP.
#define HALO()                                                       \
    {                                                                \
        float t_ = __shfl(vv3, upL, 64);                             \
        float b_ = __shfl(vv0, dnL, 64);                             \
        S[0] = top0 ? 0.f : t_;                                      \
        S[1] = vv0; S[2] = vv1; S[3] = vv2; S[4] = vv3;              \
        S[5] = bot0 ? 0.f : b_;                                      \
        _Pragma("unroll")                                            \
        for (int j = 0; j < 6; ++j) {                                \
            L[j] = dpp_left(S[j]);                                   \
            R[j] = dpp_right(S[j]);                                  \
        }                                                            \
    }

    // ---- 19 VI sweeps: barrier-free, LDS-free, packed fp32 ----
    #pragma unroll 1
    for (int it = 0; it < 19; ++it) {
        HALO();
        #pragma unroll
        for (int k = 0; k < 4; ++k) {
            pf2 a_[5];
            #pragma unroll
            for (int ap = 0; ap < 5; ++ap) a_[ap] = qr2[k][ap];
            #pragma unroll
            for (int dy = 0; dy < 3; ++dy) {
                const float tl = L[k + dy], ts = S[k + dy], tr = R[k + dy];
                pf2 vl = {tl, tl}, vs = {ts, ts}, vr = {tr, tr};
                #pragma unroll
                for (int ap = 0; ap < 5; ++ap) {
                    a_[ap] = __builtin_elementwise_fma(vl, wpk[ap * 9 + dy * 3 + 0], a_[ap]);
                    a_[ap] = __builtin_elementwise_fma(vs, wpk[ap * 9 + dy * 3 + 1], a_[ap]);
                    a_[ap] = __builtin_elementwise_fma(vr, wpk[ap * 9 + dy * 3 + 2], a_[ap]);
                }
            }
            pf2 m = __builtin_elementwise_max(
                        __builtin_elementwise_max(a_[0], a_[1]),
                        __builtin_elementwise_max(a_[2], a_[3]));
            m = __builtin_elementwise_max(m, a_[4]);
            float mk = fmaxf(m.x, m.y);
            if (k == 0) vv0 = mk; else if (k == 1) vv1 = mk;
            else if (k == 2) vv2 = mk; else vv3 = mk;
        }
    }

    // ---- one more halo for the final conv's v-taps ----
    HALO();

    // ---- final conv + gather + fc at (s1, s2) only ----
    int s1 = (int)floorf((s1f + 50.0f) / 6.25f);
    int s2 = (int)floorf((s2f + 50.0f) / 6.25f);
    s1 = min(max(s1, 0), 15);
    s2 = min(max(s2, 0), 15);

    if (rg == (s1 >> 2) && c == s2) {
        float fw[9];
        #pragma unroll
        for (int tt = 0; tt < 9; ++tt) fw[tt] = ws[19 + tt];

        float d0, d1, d2, d3;
        {
            pf2 p0 = {0.f, 0.f}, p1 = p0, p2 = p0, p3 = p0;
            #pragma unroll
            for (int ap = 0; ap < 5; ++ap) {
                const pf2 fcp = *(const pf2*)(fcw + 2 * ap);
                p0 = __builtin_elementwise_fma(qr2[0][ap], fcp, p0);
                p1 = __builtin_elementwise_fma(qr2[1][ap], fcp, p1);
                p2 = __builtin_elementwise_fma(qr2[2][ap], fcp, p2);
                p3 = __builtin_elementwise_fma(qr2[3][ap], fcp, p3);
            }
            d0 = p0.x + p0.y; d1 = p1.x + p1.y;
            d2 = p2.x + p2.y; d3 = p3.x + p3.y;
        }
        float g0 = d0, g1 = d1, g2 = d2, g3 = d3;
        #pragma unroll
        for (int dy = 0; dy < 3; ++dy) {
            const float f0 = fw[dy * 3 + 0], f1 = fw[dy * 3 + 1], f2 = fw[dy * 3 + 2];
            g0 += L[0 + dy] * f0; g0 += S[0 + dy] * f1; g0 += R[0 + dy] * f2;
            g1 += L[1 + dy] * f0; g1 += S[1 + dy] * f1; g1 += R[1 + dy] * f2;
            g2 += L[2 + dy] * f0; g2 += S[2 + dy] * f1; g2 += R[2 + dy] * f2;
            g3 += L[3 + dy] * f0; g3 += S[3 + dy] * f1; g3 += R[3 + dy] * f2;
        }
        const int kk = s1 & 3;
        float logit = (kk == 0) ? g0 : (kk == 1) ? g1 : (kk == 2) ? g2 : g3;
        out[b]       = logit;   // logits
        out[B_N + b] = 1.0f;    // softmax over length-1 axis == 1
    }
#undef HALO
}

extern "C" void kernel_launch(void* const* d_in, const int* in_sizes, int n_in,
                              void* d_out, int out_size, void* d_ws, size_t ws_size,
                              hipStream_t stream) {
    const float* X    = (const float*)d_in[0];
    const float* S1   = (const float*)d_in[1];
    const float* S2   = (const float*)d_in[2];
    const float* h_w  = (const float*)d_in[3];
    const float* h_b  = (const float*)d_in[4];
    const float* r_w  = (const float*)d_in[5];
    const float* q_w  = (const float*)d_in[6];
    const float* w    = (const float*)d_in[7];
    const float* fc_w = (const float*)d_in[8];
    float*       out  = (float*)d_out;
    float*       ws   = (float*)d_ws;

    vin_precompute<<<1, 256, 0, stream>>>(h_w, h_b, r_w, q_w, w, fc_w, ws);
    vin_kernel<<<B_N, 64, 0, stream>>>(X, S1, S2, fc_w, ws, out);
}

// Round 17
// 30.070 us; speedup vs baseline: 1.0348x; 1.0348x over previous
//
#include <hip/hip_runtime.h>

#define B_N   2048
#define LQ    10
#define LH    150

typedef float pf2 __attribute__((ext_vector_type(2)));

// ---------------- single fused kernel ----------------
// ONE WAVE per batch element (2048 blocks x 64 thr, 2 waves/SIMD).
// lane = rg*16 + c; rg owns pixel rows 4rg..4rg+3, col c.
//
// R16 structure (register-resident barrier-free VI, DPP horizontal halo,
// 2 shfl vertical halo, action-pair v_pk_fma_f32, weights in SGPRs) with the
// pre-kernel FUSED: each block redundantly computes eff_w/eff_b/fw from
// LDS-staged h_w/h_b/r_w/w/fc (L2-resident broadcast reads; ~0.4us/wave,
// interleaved across 2 waves/SIMD). Removes the serial 1-block precompute
// kernel + inter-kernel stream gap (~4-6us of the R16 31.1us total).
//
// LDS layout (floats):
//   [0,2700)     h_w      [2700,2850) h_b     [2850,3000) r_w
//   [3000,3057)  eff partials (57)    [3057,3076) eff_w[18]+eff_b
//   [3076,3166)  w (90)   [3166,3176) fc      [3176,3185) fw
//   [3200,4496)  X padded: ch*648 + (row+1)*36 + (col+1), stride 36
// No runtime indexing into register arrays (round-4 lesson).
#define HW_   0
#define HB_   2700
#define RW_   2850
#define PART_ 3000
#define EFF_  3057
#define WSL_  3076
#define FCL_  3166
#define FWL_  3176
#define XS_   3200
#define ST    36
#define SMEMN 4496

__device__ __forceinline__ float dpp_left(float x) {   // value from col c-1; 0 at c==0
    return __int_as_float(__builtin_amdgcn_update_dpp(
        0, __float_as_int(x), 0x111, 0xF, 0xF, true));  // row_shr:1
}
__device__ __forceinline__ float dpp_right(float x) {  // value from col c+1; 0 at c==15
    return __int_as_float(__builtin_amdgcn_update_dpp(
        0, __float_as_int(x), 0x101, 0xF, 0xF, true));  // row_shl:1
}

__global__ __launch_bounds__(64, 2) void vin_kernel(
    const float* __restrict__ X,   const float* __restrict__ S1,
    const float* __restrict__ S2,  const float* __restrict__ h_w,
    const float* __restrict__ h_b, const float* __restrict__ r_w,
    const float* __restrict__ qw,  const float* __restrict__ w,
    const float* __restrict__ fcw, float* __restrict__ out)
{
    __shared__ float smem[SMEMN];

    const int lane = threadIdx.x;
    const int rg   = lane >> 4;
    const int c    = lane & 15;
    const int b    = blockIdx.x;

    // ---- issue per-batch global loads first ----
    const float* Xb = X + (size_t)b * 512;
    float xreg[8];
    #pragma unroll
    for (int k = 0; k < 8; ++k) xreg[k] = Xb[lane + (k << 6)];
    const float s1f = S1[b], s2f = S2[b];

    // ---- stage weights into LDS (coalesced; L2-resident broadcast) ----
    #pragma unroll
    for (int k = 0; k < 43; ++k) {
        int idx = lane + (k << 6);
        if (idx < 2700) smem[HW_ + idx] = h_w[idx];
    }
    #pragma unroll
    for (int k = 0; k < 3; ++k) {
        int idx = lane + (k << 6);
        if (idx < 150) { smem[HB_ + idx] = h_b[idx]; smem[RW_ + idx] = r_w[idx]; }
    }
    #pragma unroll
    for (int k = 0; k < 2; ++k) {
        int idx = lane + (k << 6);
        if (idx < 90) smem[WSL_ + idx] = w[idx];
    }
    if (lane < 10) smem[FCL_ + lane] = fcw[lane];

    // ---- stage X: border-zero + interior (disjoint cells) ----
    #pragma unroll
    for (int ch = 0; ch < 2; ++ch) {
        float* Bc = smem + XS_ + ch * 648;
        if (lane < 18)      { Bc[lane] = 0.f; Bc[17 * ST + lane] = 0.f; }
        else if (lane < 34) { const int r = lane - 17; Bc[r * ST] = 0.f; Bc[r * ST + 17] = 0.f; }
    }
    #pragma unroll
    for (int k = 0; k < 8; ++k) {
        int e = lane + (k << 6);
        int ch = e >> 8, rem = e & 255;
        smem[XS_ + ch * 648 + ((rem >> 4) + 1) * ST + (rem & 15) + 1] = xreg[k];
    }
    __syncthreads();

    // ---- collapsed-weight reduce: 57 lanes x 50-chunk partials ----
    if (lane < 57) {
        const int t  = lane / 3;              // 0..18
        const int h0 = (lane - t * 3) * 50;
        float part = 0.f;
        for (int h = h0; h < h0 + 50; ++h)
            part += smem[RW_ + h] * (t < 18 ? smem[HW_ + h * 18 + t] : smem[HB_ + h]);
        smem[PART_ + lane] = part;
    }
    __syncthreads();
    if (lane < 19) {
        smem[EFF_ + lane] = smem[PART_ + lane * 3] + smem[PART_ + lane * 3 + 1]
                          + smem[PART_ + lane * 3 + 2];
    } else if (lane < 28) {
        const int t = lane - 19;
        float acc = 0.f;
        #pragma unroll
        for (int a = 0; a < LQ; ++a) acc += smem[FCL_ + a] * smem[WSL_ + a * 9 + t];
        smem[FWL_ + t] = acc;                 // fw
    }
    __syncthreads();

    float ew[19];
    #pragma unroll
    for (int tt = 0; tt < 19; ++tt) ew[tt] = smem[EFF_ + tt];

    // ---- r = conv3x3(X, eff_w) + eff_b for this lane's 4 rows (in regs) ----
    float rr0, rr1, rr2, rr3;
    {
        const float* xb = smem + XS_ + (rg << 2) * ST + c;
        float xt[2][6][3];
        #pragma unroll
        for (int ch = 0; ch < 2; ++ch)
            #pragma unroll
            for (int dy = 0; dy < 6; ++dy)
                #pragma unroll
                for (int dx = 0; dx < 3; ++dx)
                    xt[ch][dy][dx] = xb[ch * 648 + dy * ST + dx];

        #pragma unroll
        for (int k = 0; k < 4; ++k) {
            float acc = ew[18];
            #pragma unroll
            for (int ch = 0; ch < 2; ++ch)
                #pragma unroll
                for (int ky = 0; ky < 3; ++ky)
                    #pragma unroll
                    for (int kx = 0; kx < 3; ++kx)
                        acc += xt[ch][k + ky][kx] * ew[ch * 9 + ky * 3 + kx];
            if (k == 0) rr0 = acc; else if (k == 1) rr1 = acc;
            else if (k == 2) rr2 = acc; else rr3 = acc;
        }
    }

    const bool top0 = (rg == 0), bot0 = (rg == 3);
    const int  upL  = (lane - 16) & 63;
    const int  dnL  = (lane + 16) & 63;

    // ---- r halo via shuffle machinery (no LDS round-trip) ----
    float S[6], L[6], R[6];
    {
        float t_ = __shfl(rr3, upL, 64);
        float b_ = __shfl(rr0, dnL, 64);
        S[0] = top0 ? 0.f : t_;
        S[1] = rr0; S[2] = rr1; S[3] = rr2; S[4] = rr3;
        S[5] = bot0 ? 0.f : b_;
        #pragma unroll
        for (int j = 0; j < 6; ++j) { L[j] = dpp_left(S[j]); R[j] = dpp_right(S[j]); }
    }

    // ---- packed weight pairs (uniform s_loads -> SGPR pairs) ----
    // qp/wp[ap*9+t] = {q_w[2ap][t], q_w[2ap+1][t]} / {w[2ap][t], w[2ap+1][t]}
    pf2 wp[45];
    #pragma unroll
    for (int ap = 0; ap < 5; ++ap)
        #pragma unroll
        for (int tt = 0; tt < 9; ++tt)
            wp[ap * 9 + tt] = pf2{w[(2 * ap) * 9 + tt], w[(2 * ap + 1) * 9 + tt]};

    // ---- qr2[k][ap] = packed conv3x3(r, q_w) (iteration-invariant) ----
    pf2 qr2[4][5];
    #pragma unroll
    for (int k = 0; k < 4; ++k)
        #pragma unroll
        for (int ap = 0; ap < 5; ++ap) {
            pf2 acc = {0.f, 0.f};
            #pragma unroll
            for (int dy = 0; dy < 3; ++dy) {
                const float tl = L[k + dy], ts = S[k + dy], tr = R[k + dy];
                pf2 vl = {tl, tl}, vs = {ts, ts}, vr = {tr, tr};
                pf2 q0 = {qw[(2*ap)*9 + dy*3 + 0], qw[(2*ap+1)*9 + dy*3 + 0]};
                pf2 q1 = {qw[(2*ap)*9 + dy*3 + 1], qw[(2*ap+1)*9 + dy*3 + 1]};
                pf2 q2 = {qw[(2*ap)*9 + dy*3 + 2], qw[(2*ap+1)*9 + dy*3 + 2]};
                acc = __builtin_elementwise_fma(vl, q0, acc);
                acc = __builtin_elementwise_fma(vs, q1, acc);
                acc = __builtin_elementwise_fma(vr, q2, acc);
            }
            qr2[k][ap] = acc;
        }

    // ---- v0 = max over 10 actions, register-resident ----
    float vv0, vv1, vv2, vv3;
    {
        pf2 m0 = __builtin_elementwise_max(
                     __builtin_elementwise_max(qr2[0][0], qr2[0][1]),
                     __builtin_elementwise_max(qr2[0][2], qr2[0][3]));
        m0 = __builtin_elementwise_max(m0, qr2[0][4]);
        vv0 = fmaxf(m0.x, m0.y);
        pf2 m1 = __builtin_elementwise_max(
                     __builtin_elementwise_max(qr2[1][0], qr2[1][1]),
                     __builtin_elementwise_max(qr2[1][2], qr2[1][3]));
        m1 = __builtin_elementwise_max(m1, qr2[1][4]);
        vv1 = fmaxf(m1.x, m1.y);
        pf2 m2 = __builtin_elementwise_max(
                     __builtin_elementwise_max(qr2[2][0], qr2[2][1]),
                     __builtin_elementwise_max(qr2[2][2], qr2[2][3]));
        m2 = __builtin_elementwise_max(m2, qr2[2][4]);
        vv2 = fmaxf(m2.x, m2.y);
        pf2 m3 = __builtin_elementwise_max(
                     __builtin_elementwise_max(qr2[3][0], qr2[3][1]),
                     __builtin_elementwise_max(qr2[3][2], qr2[3][3]));
        m3 = __builtin_elementwise_max(m3, qr2[3][4]);
        vv3 = fmaxf(m3.x, m3.y);
    }

    // S[j] = own-column v at pixel row 4rg-1+j; L/R = cols c-1/c+1 via DPP.
#define HALO()                                                       \
    {                                                                \
        float t_ = __shfl(vv3, upL, 64);                             \
        float b_ = __shfl(vv0, dnL, 64);                             \
        S[0] = top0 ? 0.f : t_;                                      \
        S[1] = vv0; S[2] = vv1; S[3] = vv2; S[4] = vv3;              \
        S[5] = bot0 ? 0.f : b_;                                      \
        _Pragma("unroll")                                            \
        for (int j = 0; j < 6; ++j) {                                \
            L[j] = dpp_left(S[j]);                                   \
            R[j] = dpp_right(S[j]);                                  \
        }                                                            \
    }

    // ---- 19 VI sweeps: barrier-free, LDS-free, packed fp32 ----
    #pragma unroll 1
    for (int it = 0; it < 19; ++it) {
        HALO();
        #pragma unroll
        for (int k = 0; k < 4; ++k) {
            pf2 a_[5];
            #pragma unroll
            for (int ap = 0; ap < 5; ++ap) a_[ap] = qr2[k][ap];
            #pragma unroll
            for (int dy = 0; dy < 3; ++dy) {
                const float tl = L[k + dy], ts = S[k + dy], tr = R[k + dy];
                pf2 vl = {tl, tl}, vs = {ts, ts}, vr = {tr, tr};
                #pragma unroll
                for (int ap = 0; ap < 5; ++ap) {
                    a_[ap] = __builtin_elementwise_fma(vl, wp[ap * 9 + dy * 3 + 0], a_[ap]);
                    a_[ap] = __builtin_elementwise_fma(vs, wp[ap * 9 + dy * 3 + 1], a_[ap]);
                    a_[ap] = __builtin_elementwise_fma(vr, wp[ap * 9 + dy * 3 + 2], a_[ap]);
                }
            }
            pf2 m = __builtin_elementwise_max(
                        __builtin_elementwise_max(a_[0], a_[1]),
                        __builtin_elementwise_max(a_[2], a_[3]));
            m = __builtin_elementwise_max(m, a_[4]);
            float mk = fmaxf(m.x, m.y);
            if (k == 0) vv0 = mk; else if (k == 1) vv1 = mk;
            else if (k == 2) vv2 = mk; else vv3 = mk;
        }
    }

    // ---- one more halo for the final conv's v-taps ----
    HALO();

    // ---- final conv + gather + fc at (s1, s2) only ----
    int s1 = (int)floorf((s1f + 50.0f) / 6.25f);
    int s2 = (int)floorf((s2f + 50.0f) / 6.25f);
    s1 = min(max(s1, 0), 15);
    s2 = min(max(s2, 0), 15);

    if (rg == (s1 >> 2) && c == s2) {
        float fw[9];
        #pragma unroll
        for (int tt = 0; tt < 9; ++tt) fw[tt] = smem[FWL_ + tt];

        float d0, d1, d2, d3;
        {
            pf2 p0 = {0.f, 0.f}, p1 = p0, p2 = p0, p3 = p0;
            #pragma unroll
            for (int ap = 0; ap < 5; ++ap) {
                const pf2 fcp = *(const pf2*)(fcw + 2 * ap);
                p0 = __builtin_elementwise_fma(qr2[0][ap], fcp, p0);
                p1 = __builtin_elementwise_fma(qr2[1][ap], fcp, p1);
                p2 = __builtin_elementwise_fma(qr2[2][ap], fcp, p2);
                p3 = __builtin_elementwise_fma(qr2[3][ap], fcp, p3);
            }
            d0 = p0.x + p0.y; d1 = p1.x + p1.y;
            d2 = p2.x + p2.y; d3 = p3.x + p3.y;
        }
        float g0 = d0, g1 = d1, g2 = d2, g3 = d3;
        #pragma unroll
        for (int dy = 0; dy < 3; ++dy) {
            const float f0 = fw[dy * 3 + 0], f1 = fw[dy * 3 + 1], f2 = fw[dy * 3 + 2];
            g0 += L[0 + dy] * f0; g0 += S[0 + dy] * f1; g0 += R[0 + dy] * f2;
            g1 += L[1 + dy] * f0; g1 += S[1 + dy] * f1; g1 += R[1 + dy] * f2;
            g2 += L[2 + dy] * f0; g2 += S[2 + dy] * f1; g2 += R[2 + dy] * f2;
            g3 += L[3 + dy] * f0; g3 += S[3 + dy] * f1; g3 += R[3 + dy] * f2;
        }
        const int kk = s1 & 3;
        float logit = (kk == 0) ? g0 : (kk == 1) ? g1 : (kk == 2) ? g2 : g3;
        out[b]       = logit;   // logits
        out[B_N + b] = 1.0f;    // softmax over length-1 axis == 1
    }
#undef HALO
}

extern "C" void kernel_launch(void* const* d_in, const int* in_sizes, int n_in,
                              void* d_out, int out_size, void* d_ws, size_t ws_size,
                              hipStream_t stream) {
    const float* X    = (const float*)d_in[0];
    const float* S1   = (const float*)d_in[1];
    const float* S2   = (const float*)d_in[2];
    const float* h_w  = (const float*)d_in[3];
    const float* h_b  = (const float*)d_in[4];
    const float* r_w  = (const float*)d_in[5];
    const float* q_w  = (const float*)d_in[6];
    const float* w    = (const float*)d_in[7];
    const float* fc_w = (const float*)d_in[8];
    float*       out  = (float*)d_out;

    vin_kernel<<<B_N, 64, 0, stream>>>(X, S1, S2, h_w, h_b, r_w, q_w, w, fc_w, out);
}